// Round 5
// baseline (328.633 us; speedup 1.0000x reference)
//
#include <hip/hip_runtime.h>
#include <cstdint>
#include <cstddef>

// Attention: B=4, S=2048, H=1024 (single "head", d=1024). fp32 I/O buffers.
// Pipeline: convert x,W* to bf16 in ws ; Q/K = xb·Wᵀ+b ; Vt = (xb·Wvᵀ+bv)ᵀ ;
//           Sc = Q·Kᵀ/32 (fp16) ; P = softmax(Sc) (bf16) ; out = P·Vtᵀ (fp32).
// R4: pipeline verified correct (328µs, absmax 2e-3), GEMMs at m93-class 490TF
//     (register staging, VALUBusy>MfmaUtil, 8-way LDS read conflicts).
// R5: restore async global_load_lds width=16 staging (exonerated — R1's NaN
//     was the fp32/bf16 dtype bug, not staging) + XOR bank swizzle
//     c' = c ^ ((row>>1)&3) on the global chunk -> fragment reads drop from
//     8-way to 2-way (free, m136) while LDS stays lane-linear for the DMA.
// ws layout (102 MB): [0,16M) xb ; [16,18M) Wqb ; [18,20M) Wkb ; [20,22M) Wvb ;
//   [22,38M) Q ; [38,54M) Kp ; [54,70M) Vt ; [70,102M) Sc fp16 ;
//   P overlays [22,54M) (Q|Kp dead after scores GEMM).

typedef __bf16 bf16;
typedef _Float16 f16;
typedef __bf16 bf16x8 __attribute__((ext_vector_type(8)));
typedef __bf16 bf16x4 __attribute__((ext_vector_type(4)));
typedef float f32x4 __attribute__((ext_vector_type(4)));

#define BM 128
#define BN 128
#define BK 32

// fp32 -> bf16 convert, 4 elements/thread.
__global__ __launch_bounds__(256)
void cvt_f32_bf16(const float* __restrict__ src, bf16* __restrict__ dst, int n4)
{
    const int i = blockIdx.x * 256 + threadIdx.x;
    if (i < n4) {
        f32x4 v = *(const f32x4*)(src + 4 * (size_t)i);
        bf16x4 o;
#pragma unroll
        for (int r = 0; r < 4; ++r) o[r] = (bf16)v[r];
        *(bf16x4*)(dst + 4 * (size_t)i) = o;
    }
}

// Stage one 128x32 bf16 tile (8 KB) global -> LDS via global_load_lds w=16.
// Lane handling tile position p = issue*256 + tid reads global chunk
// c = (p&3) ^ ((row>>1)&3) of row p>>2; LDS stays linear in p (DMA order:
// wave-uniform base + lane*16, m104). Swizzle undone at read_frag.
__device__ __forceinline__ void stage_tile(const bf16* __restrict__ g, int ld,
                                           bf16* lds_generic, int tid)
{
    auto lds3 = (__attribute__((address_space(3))) char*)lds_generic;
    const int wave = tid >> 6;
#pragma unroll
    for (int issue = 0; issue < 2; ++issue) {
        const int p   = issue * 256 + tid;
        const int row = p >> 2;
        const int cp  = p & 3;
        const int c   = cp ^ ((row >> 1) & 3);
        const bf16* gp = g + (size_t)row * ld + c * 8;
        const unsigned wave_base = (unsigned)(issue * 4096 + wave * 1024);
        __builtin_amdgcn_global_load_lds(
            (const __attribute__((address_space(1))) void*)gp,
            (__attribute__((address_space(3))) void*)(lds3 + wave_base),
            16, 0, 0);
    }
}

// Read an 8-element (16B) fragment at (row, k-chunk=quad) honoring the swizzle.
__device__ __forceinline__ bf16x8 read_frag(const bf16* lds, int row, int quad)
{
    const int c = quad ^ ((row >> 1) & 3);
    return *(const bf16x8*)(lds + row * BK + c * 8);
}

// OUTMODE: 0 = bf16 out + bias (Q/K proj)
//          1 = bf16 out transposed per batch (Vt) + bias
//          2 = f16 out, scaled by alpha (scores)
//          3 = f32 out, no bias (final O -> d_out)
template <int OUTMODE>
__global__ __launch_bounds__(256)
void gemm_bt(const bf16* __restrict__ A, const bf16* __restrict__ Bm,
             const float* __restrict__ bias, void* __restrict__ C,
             int K, int N, float alpha, long zA, long zB, long zC)
{
    __shared__ alignas(16) bf16 As[BM * BK];
    __shared__ alignas(16) bf16 Bs[BN * BK];

    const int tid  = threadIdx.x;
    const int lane = tid & 63;
    const int wid  = tid >> 6;
    const int wr   = (wid >> 1) * 64;   // wave row offset in tile
    const int wc   = (wid & 1) * 64;    // wave col offset in tile
    const int quad = lane >> 4;
    const int l16  = lane & 15;

    const int m0 = blockIdx.y * BM;
    const int n0 = blockIdx.x * BN;
    const int z  = blockIdx.z;

    const bf16* Ab = A + (size_t)z * zA + (size_t)m0 * K;
    const bf16* Bb = Bm + (size_t)z * zB + (size_t)n0 * K;

    f32x4 acc[4][4] = {};

    for (int k0 = 0; k0 < K; k0 += BK) {
        __syncthreads();   // previous iteration's LDS reads complete
        stage_tile(Ab + k0, K, As, tid);
        stage_tile(Bb + k0, K, Bs, tid);
        __syncthreads();   // drains vmcnt(0): tiles visible

        bf16x8 af[4], bfr[4];
#pragma unroll
        for (int i = 0; i < 4; ++i) af[i]  = read_frag(As, wr + i * 16 + l16, quad);
#pragma unroll
        for (int j = 0; j < 4; ++j) bfr[j] = read_frag(Bs, wc + j * 16 + l16, quad);

#pragma unroll
        for (int i = 0; i < 4; ++i)
#pragma unroll
            for (int j = 0; j < 4; ++j)
                acc[i][j] = __builtin_amdgcn_mfma_f32_16x16x32_bf16(
                    af[i], bfr[j], acc[i][j], 0, 0, 0);
    }

    // Epilogue. C/D layout (verified m89): col = lane&15, row = quad*4 + reg.
#pragma unroll
    for (int j = 0; j < 4; ++j) {
        const int col = n0 + wc + j * 16 + l16;
        float bj = 0.f;
        if (OUTMODE == 0 || OUTMODE == 1) bj = bias[col];
#pragma unroll
        for (int i = 0; i < 4; ++i) {
            const int rbase = m0 + wr + i * 16 + quad * 4;
            if (OUTMODE == 2) {
                f16* Cf = (f16*)C + (size_t)z * zC;
#pragma unroll
                for (int r = 0; r < 4; ++r)
                    Cf[(size_t)(rbase + r) * N + col] = (f16)(acc[i][j][r] * alpha);
            } else if (OUTMODE == 3) {
                float* Cf = (float*)C + (size_t)z * zC;
#pragma unroll
                for (int r = 0; r < 4; ++r)
                    Cf[(size_t)(rbase + r) * N + col] = acc[i][j][r];
            } else if (OUTMODE == 1) {
                // Vt[b][col][s] = V[b*2048+s][col]; rows of one MFMA quad are
                // 4 consecutive s -> one 8B same-type vector store.
                bf16* Cb = (bf16*)C;
                const int b = rbase >> 11;
                const int s = rbase & 2047;
                bf16x4 tmp;
#pragma unroll
                for (int r = 0; r < 4; ++r) tmp[r] = (bf16)(acc[i][j][r] + bj);
                *(bf16x4*)(Cb + (((size_t)((b << 10) + col)) << 11) + s) = tmp;
            } else {
                bf16* Cb = (bf16*)C + (size_t)z * zC;
#pragma unroll
                for (int r = 0; r < 4; ++r)
                    Cb[(size_t)(rbase + r) * N + col] = (bf16)(acc[i][j][r] + bj);
            }
        }
    }
}

__device__ __forceinline__ float wred_max(float v)
{
#pragma unroll
    for (int o = 32; o > 0; o >>= 1) v = fmaxf(v, __shfl_xor(v, o, 64));
    return v;
}
__device__ __forceinline__ float wred_sum(float v)
{
#pragma unroll
    for (int o = 32; o > 0; o >>= 1) v += __shfl_xor(v, o, 64);
    return v;
}

__global__ __launch_bounds__(256)
void softmax_rows(const f16* __restrict__ Sc, bf16* __restrict__ P)
{
    constexpr int NC = 2048;
    const size_t row = blockIdx.x;
    const f16* src = Sc + row * NC;
    bf16* dst = P + row * NC;
    const int tid = threadIdx.x;

    float v[8];
    float m = -3.4e38f;
#pragma unroll
    for (int i = 0; i < 8; ++i) {
        v[i] = (float)src[tid + 256 * i];
        m = fmaxf(m, v[i]);
    }
    m = wred_max(m);

    __shared__ float redm[4], reds[4];
    if ((tid & 63) == 0) redm[tid >> 6] = m;
    __syncthreads();
    m = fmaxf(fmaxf(redm[0], redm[1]), fmaxf(redm[2], redm[3]));

    float s = 0.f;
#pragma unroll
    for (int i = 0; i < 8; ++i) { v[i] = __expf(v[i] - m); s += v[i]; }
    s = wred_sum(s);
    if ((tid & 63) == 0) reds[tid >> 6] = s;
    __syncthreads();
    s = reds[0] + reds[1] + reds[2] + reds[3];

    const float inv = 1.f / s;
#pragma unroll
    for (int i = 0; i < 8; ++i) dst[tid + 256 * i] = (bf16)(v[i] * inv);
}

extern "C" void kernel_launch(void* const* d_in, const int* in_sizes, int n_in,
                              void* d_out, int out_size, void* d_ws, size_t ws_size,
                              hipStream_t stream)
{
    constexpr int B = 4, S = 2048, H = 1024;
    const float* x  = (const float*)d_in[0];
    const float* Wq = (const float*)d_in[1];
    const float* bq = (const float*)d_in[2];
    const float* Wk = (const float*)d_in[3];
    const float* bk = (const float*)d_in[4];
    const float* Wv = (const float*)d_in[5];
    const float* bv = (const float*)d_in[6];
    float* out = (float*)d_out;

    char* ws = (char*)d_ws;
    bf16* xb  = (bf16*)ws;                         // 16 MB
    bf16* Wqb = (bf16*)(ws + (size_t)(16 << 20));  //  2 MB
    bf16* Wkb = (bf16*)(ws + (size_t)(18 << 20));  //  2 MB
    bf16* Wvb = (bf16*)(ws + (size_t)(20 << 20));  //  2 MB
    bf16* Q   = (bf16*)(ws + (size_t)(22 << 20));  // 16 MB
    bf16* Kp  = (bf16*)(ws + (size_t)(38 << 20));  // 16 MB
    bf16* Vt  = (bf16*)(ws + (size_t)(54 << 20));  // 16 MB
    f16*  Sc  = (f16*) (ws + (size_t)(70 << 20));  // 32 MB (fp16 scores)
    bf16* P   = (bf16*)(ws + (size_t)(22 << 20));  // 32 MB, overlays Q|Kp

    dim3 blk(256, 1, 1);

    // fp32 -> bf16 conversions
    cvt_f32_bf16<<<dim3((B * S * H) / 1024), blk, 0, stream>>>(x, xb, (B * S * H) / 4);
    cvt_f32_bf16<<<dim3((H * H) / 1024), blk, 0, stream>>>(Wq, Wqb, (H * H) / 4);
    cvt_f32_bf16<<<dim3((H * H) / 1024), blk, 0, stream>>>(Wk, Wkb, (H * H) / 4);
    cvt_f32_bf16<<<dim3((H * H) / 1024), blk, 0, stream>>>(Wv, Wvb, (H * H) / 4);

    // Projections: M = B*S = 8192, N = H, K = H
    gemm_bt<0><<<dim3(H / BN, (B * S) / BM, 1), blk, 0, stream>>>(
        xb, Wqb, bq, Q, H, H, 1.0f, 0, 0, 0);
    gemm_bt<0><<<dim3(H / BN, (B * S) / BM, 1), blk, 0, stream>>>(
        xb, Wkb, bk, Kp, H, H, 1.0f, 0, 0, 0);
    gemm_bt<1><<<dim3(H / BN, (B * S) / BM, 1), blk, 0, stream>>>(
        xb, Wvb, bv, Vt, H, H, 1.0f, 0, 0, 0);

    // Scores: per batch (grid.z), Sc = Q·Kᵀ / 32, fp16
    gemm_bt<2><<<dim3(S / BN, S / BM, B), blk, 0, stream>>>(
        Q, Kp, nullptr, Sc, H, S, 0.03125f,
        (long)S * H, (long)S * H, (long)S * S);

    // Row softmax: 8192 rows of 2048
    softmax_rows<<<dim3(B * S), blk, 0, stream>>>(Sc, P);

    // O = P·Vtᵀ -> out (fp32)
    gemm_bt<3><<<dim3(H / BN, S / BM, B), blk, 0, stream>>>(
        P, Vt, nullptr, out, S, H, 1.0f,
        (long)S * S, (long)H * S, (long)S * H);
}

// Round 6
// 285.466 us; speedup vs baseline: 1.1512x; 1.1512x over previous
//
#include <hip/hip_runtime.h>
#include <cstdint>
#include <cstddef>

// Attention: B=4, S=2048, H=1024 (single "head", d=1024). fp32 I/O buffers.
// Pipeline: convert x,W* to bf16 in ws ; Q/K = xb·Wᵀ+b ; Vt = (xb·Wvᵀ+bv)ᵀ ;
//           Sc = Q·Kᵀ/32 (fp16) ; P = softmax(Sc) (bf16) ; out = P·Vtᵀ (fp32).
// R5 post-mortem: bank conflicts 4.2e6->0 but dur unchanged (480TF) — kernel
//   is barrier-drain latency-bound (matrix pipe ~6% busy from raw counts;
//   each BK=32 iter pays a vmcnt(0) drain ~200-900cyc; compute/iter ~170cyc).
// R6: BK=64 — halve the number of barrier drains per FLOP. LDS 32KB/block
//   (still >=4 blocks/CU; grid caps at 4/CU). Swizzle: LDS[row][cp] holds
//   global chunk cp^(row&7); fragment reads at chunk h*4+quad spread 16 lanes
//   over 8 slots -> 2-way (free, m136).
// ws layout (102 MB): [0,16M) xb ; [16,18M) Wqb ; [18,20M) Wkb ; [20,22M) Wvb ;
//   [22,38M) Q ; [38,54M) Kp ; [54,70M) Vt ; [70,102M) Sc fp16 ;
//   P overlays [22,54M) (Q|Kp dead after scores GEMM).

typedef __bf16 bf16;
typedef _Float16 f16;
typedef __bf16 bf16x8 __attribute__((ext_vector_type(8)));
typedef __bf16 bf16x4 __attribute__((ext_vector_type(4)));
typedef float f32x4 __attribute__((ext_vector_type(4)));

#define BM 128
#define BN 128
#define BK 64

// fp32 -> bf16 convert, 4 elements/thread.
__global__ __launch_bounds__(256)
void cvt_f32_bf16(const float* __restrict__ src, bf16* __restrict__ dst, int n4)
{
    const int i = blockIdx.x * 256 + threadIdx.x;
    if (i < n4) {
        f32x4 v = *(const f32x4*)(src + 4 * (size_t)i);
        bf16x4 o;
#pragma unroll
        for (int r = 0; r < 4; ++r) o[r] = (bf16)v[r];
        *(bf16x4*)(dst + 4 * (size_t)i) = o;
    }
}

// Stage one 128x64 bf16 tile (16 KB) global -> LDS via global_load_lds w=16.
// Tile = 128 rows x 8 chunks (16B each). Lane at linear chunk p stores LDS
// slot p (DMA: wave-uniform base + lane*16) and fetches global chunk
// c = (p&7) ^ ((p>>3)&7) of row p>>3.
__device__ __forceinline__ void stage_tile(const bf16* __restrict__ g, int ld,
                                           bf16* lds_generic, int tid)
{
    auto lds3 = (__attribute__((address_space(3))) char*)lds_generic;
    const int wave = tid >> 6;
#pragma unroll
    for (int issue = 0; issue < 4; ++issue) {
        const int p   = issue * 256 + tid;
        const int row = p >> 3;
        const int cp  = p & 7;
        const int c   = cp ^ (row & 7);
        const bf16* gp = g + (size_t)row * ld + c * 8;
        const unsigned wave_base = (unsigned)(issue * 4096 + wave * 1024);
        __builtin_amdgcn_global_load_lds(
            (const __attribute__((address_space(1))) void*)gp,
            (__attribute__((address_space(3))) void*)(lds3 + wave_base),
            16, 0, 0);
    }
}

// Read the 16B fragment holding global chunk `chunk` (0..7) of `row`.
__device__ __forceinline__ bf16x8 read_frag(const bf16* lds, int row, int chunk)
{
    const int cp = chunk ^ (row & 7);
    return *(const bf16x8*)(lds + row * BK + cp * 8);
}

// OUTMODE: 0 = bf16 out + bias (Q/K proj)
//          1 = bf16 out transposed per batch (Vt) + bias
//          2 = f16 out, scaled by alpha (scores)
//          3 = f32 out, no bias (final O -> d_out)
template <int OUTMODE>
__global__ __launch_bounds__(256)
void gemm_bt(const bf16* __restrict__ A, const bf16* __restrict__ Bm,
             const float* __restrict__ bias, void* __restrict__ C,
             int K, int N, float alpha, long zA, long zB, long zC)
{
    __shared__ alignas(16) bf16 As[BM * BK];
    __shared__ alignas(16) bf16 Bs[BN * BK];

    const int tid  = threadIdx.x;
    const int lane = tid & 63;
    const int wid  = tid >> 6;
    const int wr   = (wid >> 1) * 64;   // wave row offset in tile
    const int wc   = (wid & 1) * 64;    // wave col offset in tile
    const int quad = lane >> 4;
    const int l16  = lane & 15;

    const int m0 = blockIdx.y * BM;
    const int n0 = blockIdx.x * BN;
    const int z  = blockIdx.z;

    const bf16* Ab = A + (size_t)z * zA + (size_t)m0 * K;
    const bf16* Bb = Bm + (size_t)z * zB + (size_t)n0 * K;

    f32x4 acc[4][4] = {};

    for (int k0 = 0; k0 < K; k0 += BK) {
        __syncthreads();   // previous iteration's LDS reads complete
        stage_tile(Ab + k0, K, As, tid);
        stage_tile(Bb + k0, K, Bs, tid);
        __syncthreads();   // drains vmcnt(0): tiles visible

#pragma unroll
        for (int h = 0; h < 2; ++h) {
            bf16x8 af[4], bfr[4];
#pragma unroll
            for (int i = 0; i < 4; ++i)
                af[i]  = read_frag(As, wr + i * 16 + l16, h * 4 + quad);
#pragma unroll
            for (int j = 0; j < 4; ++j)
                bfr[j] = read_frag(Bs, wc + j * 16 + l16, h * 4 + quad);

#pragma unroll
            for (int i = 0; i < 4; ++i)
#pragma unroll
                for (int j = 0; j < 4; ++j)
                    acc[i][j] = __builtin_amdgcn_mfma_f32_16x16x32_bf16(
                        af[i], bfr[j], acc[i][j], 0, 0, 0);
        }
    }

    // Epilogue. C/D layout (verified m89): col = lane&15, row = quad*4 + reg.
#pragma unroll
    for (int j = 0; j < 4; ++j) {
        const int col = n0 + wc + j * 16 + l16;
        float bj = 0.f;
        if (OUTMODE == 0 || OUTMODE == 1) bj = bias[col];
#pragma unroll
        for (int i = 0; i < 4; ++i) {
            const int rbase = m0 + wr + i * 16 + quad * 4;
            if (OUTMODE == 2) {
                f16* Cf = (f16*)C + (size_t)z * zC;
#pragma unroll
                for (int r = 0; r < 4; ++r)
                    Cf[(size_t)(rbase + r) * N + col] = (f16)(acc[i][j][r] * alpha);
            } else if (OUTMODE == 3) {
                float* Cf = (float*)C + (size_t)z * zC;
#pragma unroll
                for (int r = 0; r < 4; ++r)
                    Cf[(size_t)(rbase + r) * N + col] = acc[i][j][r];
            } else if (OUTMODE == 1) {
                // Vt[b][col][s] = V[b*2048+s][col]; rows of one MFMA quad are
                // 4 consecutive s -> one 8B same-type vector store.
                bf16* Cb = (bf16*)C;
                const int b = rbase >> 11;
                const int s = rbase & 2047;
                bf16x4 tmp;
#pragma unroll
                for (int r = 0; r < 4; ++r) tmp[r] = (bf16)(acc[i][j][r] + bj);
                *(bf16x4*)(Cb + (((size_t)((b << 10) + col)) << 11) + s) = tmp;
            } else {
                bf16* Cb = (bf16*)C + (size_t)z * zC;
#pragma unroll
                for (int r = 0; r < 4; ++r)
                    Cb[(size_t)(rbase + r) * N + col] = (bf16)(acc[i][j][r] + bj);
            }
        }
    }
}

__device__ __forceinline__ float wred_max(float v)
{
#pragma unroll
    for (int o = 32; o > 0; o >>= 1) v = fmaxf(v, __shfl_xor(v, o, 64));
    return v;
}
__device__ __forceinline__ float wred_sum(float v)
{
#pragma unroll
    for (int o = 32; o > 0; o >>= 1) v += __shfl_xor(v, o, 64);
    return v;
}

__global__ __launch_bounds__(256)
void softmax_rows(const f16* __restrict__ Sc, bf16* __restrict__ P)
{
    constexpr int NC = 2048;
    const size_t row = blockIdx.x;
    const f16* src = Sc + row * NC;
    bf16* dst = P + row * NC;
    const int tid = threadIdx.x;

    float v[8];
    float m = -3.4e38f;
#pragma unroll
    for (int i = 0; i < 8; ++i) {
        v[i] = (float)src[tid + 256 * i];
        m = fmaxf(m, v[i]);
    }
    m = wred_max(m);

    __shared__ float redm[4], reds[4];
    if ((tid & 63) == 0) redm[tid >> 6] = m;
    __syncthreads();
    m = fmaxf(fmaxf(redm[0], redm[1]), fmaxf(redm[2], redm[3]));

    float s = 0.f;
#pragma unroll
    for (int i = 0; i < 8; ++i) { v[i] = __expf(v[i] - m); s += v[i]; }
    s = wred_sum(s);
    if ((tid & 63) == 0) reds[tid >> 6] = s;
    __syncthreads();
    s = reds[0] + reds[1] + reds[2] + reds[3];

    const float inv = 1.f / s;
#pragma unroll
    for (int i = 0; i < 8; ++i) dst[tid + 256 * i] = (bf16)(v[i] * inv);
}

extern "C" void kernel_launch(void* const* d_in, const int* in_sizes, int n_in,
                              void* d_out, int out_size, void* d_ws, size_t ws_size,
                              hipStream_t stream)
{
    constexpr int B = 4, S = 2048, H = 1024;
    const float* x  = (const float*)d_in[0];
    const float* Wq = (const float*)d_in[1];
    const float* bq = (const float*)d_in[2];
    const float* Wk = (const float*)d_in[3];
    const float* bk = (const float*)d_in[4];
    const float* Wv = (const float*)d_in[5];
    const float* bv = (const float*)d_in[6];
    float* out = (float*)d_out;

    char* ws = (char*)d_ws;
    bf16* xb  = (bf16*)ws;                         // 16 MB
    bf16* Wqb = (bf16*)(ws + (size_t)(16 << 20));  //  2 MB
    bf16* Wkb = (bf16*)(ws + (size_t)(18 << 20));  //  2 MB
    bf16* Wvb = (bf16*)(ws + (size_t)(20 << 20));  //  2 MB
    bf16* Q   = (bf16*)(ws + (size_t)(22 << 20));  // 16 MB
    bf16* Kp  = (bf16*)(ws + (size_t)(38 << 20));  // 16 MB
    bf16* Vt  = (bf16*)(ws + (size_t)(54 << 20));  // 16 MB
    f16*  Sc  = (f16*) (ws + (size_t)(70 << 20));  // 32 MB (fp16 scores)
    bf16* P   = (bf16*)(ws + (size_t)(22 << 20));  // 32 MB, overlays Q|Kp

    dim3 blk(256, 1, 1);

    // fp32 -> bf16 conversions
    cvt_f32_bf16<<<dim3((B * S * H) / 1024), blk, 0, stream>>>(x, xb, (B * S * H) / 4);
    cvt_f32_bf16<<<dim3((H * H) / 1024), blk, 0, stream>>>(Wq, Wqb, (H * H) / 4);
    cvt_f32_bf16<<<dim3((H * H) / 1024), blk, 0, stream>>>(Wk, Wkb, (H * H) / 4);
    cvt_f32_bf16<<<dim3((H * H) / 1024), blk, 0, stream>>>(Wv, Wvb, (H * H) / 4);

    // Projections: M = B*S = 8192, N = H, K = H
    gemm_bt<0><<<dim3(H / BN, (B * S) / BM, 1), blk, 0, stream>>>(
        xb, Wqb, bq, Q, H, H, 1.0f, 0, 0, 0);
    gemm_bt<0><<<dim3(H / BN, (B * S) / BM, 1), blk, 0, stream>>>(
        xb, Wkb, bk, Kp, H, H, 1.0f, 0, 0, 0);
    gemm_bt<1><<<dim3(H / BN, (B * S) / BM, 1), blk, 0, stream>>>(
        xb, Wvb, bv, Vt, H, H, 1.0f, 0, 0, 0);

    // Scores: per batch (grid.z), Sc = Q·Kᵀ / 32, fp16
    gemm_bt<2><<<dim3(S / BN, S / BM, B), blk, 0, stream>>>(
        Q, Kp, nullptr, Sc, H, S, 0.03125f,
        (long)S * H, (long)S * H, (long)S * S);

    // Row softmax: 8192 rows of 2048
    softmax_rows<<<dim3(B * S), blk, 0, stream>>>(Sc, P);

    // O = P·Vtᵀ -> out (fp32)
    gemm_bt<3><<<dim3(H / BN, S / BM, B), blk, 0, stream>>>(
        P, Vt, nullptr, out, S, H, 1.0f,
        (long)S * S, (long)H * S, (long)S * H);
}

// Round 7
// 264.111 us; speedup vs baseline: 1.2443x; 1.0809x over previous
//
#include <hip/hip_runtime.h>
#include <cstdint>
#include <cstddef>

// Attention: B=4, S=2048, H=1024 (single "head", d=1024). fp32 I/O buffers.
// Pipeline: cvt x,W* to bf16 ; fused QKV GEMM (N=3072, writes Q,K,Vt) ;
//           Sc = Q·Kᵀ/32 (fp16) ; P = softmax(Sc) (bf16) ; out = P·Vtᵀ (fp32).
// R6 post-mortem: BK=64 win (285µs) but per-iter wall ~2120cyc vs ~250cyc
//   compute — the 2-barrier stage->drain->compute shape exposes full load
//   latency every iteration; projections at 2 blk/CU are occupancy-starved.
// R7: (a) QKV fused into one N=3072 dispatch (6 blk/CU); (b) LDS double-buffer
//   with cross-iteration prefetch — ONE barrier per iter, loads for tile k+1
//   issued after the barrier publishing tile k, so the vmcnt(0) drain at the
//   next barrier is hidden behind tile k's compute.
// ws layout (102 MB): [0,16M) xb ; [16,22M) Wqkv bf16 (Wq|Wk|Wv, contiguous) ;
//   [22,38M) Q ; [38,54M) Kp ; [54,70M) Vt ; [70,102M) Sc fp16 ;
//   P overlays [22,54M) (Q|Kp dead after scores GEMM).

typedef __bf16 bf16;
typedef _Float16 f16;
typedef __bf16 bf16x8 __attribute__((ext_vector_type(8)));
typedef __bf16 bf16x4 __attribute__((ext_vector_type(4)));
typedef float f32x4 __attribute__((ext_vector_type(4)));

#define BM 128
#define BN 128
#define BK 64

// fp32 -> bf16 convert, 4 elements/thread.
__global__ __launch_bounds__(256)
void cvt_f32_bf16(const float* __restrict__ src, bf16* __restrict__ dst, int n4)
{
    const int i = blockIdx.x * 256 + threadIdx.x;
    if (i < n4) {
        f32x4 v = *(const f32x4*)(src + 4 * (size_t)i);
        bf16x4 o;
#pragma unroll
        for (int r = 0; r < 4; ++r) o[r] = (bf16)v[r];
        *(bf16x4*)(dst + 4 * (size_t)i) = o;
    }
}

// Stage one 128x64 bf16 tile (16 KB) global -> LDS via global_load_lds w=16.
// Tile = 128 rows x 8 chunks (16B each). Lane at linear chunk p stores LDS
// slot p (DMA: wave-uniform base + lane*16, m104) and fetches global chunk
// c = (p&7) ^ (row&7) of row p>>3 (bank swizzle; fragment reads 2-way = free).
__device__ __forceinline__ void stage_tile(const bf16* __restrict__ g, int ld,
                                           bf16* lds_generic, int tid)
{
    auto lds3 = (__attribute__((address_space(3))) char*)lds_generic;
    const int wave = tid >> 6;
#pragma unroll
    for (int issue = 0; issue < 4; ++issue) {
        const int p   = issue * 256 + tid;
        const int row = p >> 3;
        const int cp  = p & 7;
        const int c   = cp ^ (row & 7);
        const bf16* gp = g + (size_t)row * ld + c * 8;
        const unsigned wave_base = (unsigned)(issue * 4096 + wave * 1024);
        __builtin_amdgcn_global_load_lds(
            (const __attribute__((address_space(1))) void*)gp,
            (__attribute__((address_space(3))) void*)(lds3 + wave_base),
            16, 0, 0);
    }
}

// Read the 16B fragment holding global chunk `chunk` (0..7) of `row`.
__device__ __forceinline__ bf16x8 read_frag(const bf16* lds, int row, int chunk)
{
    const int cp = chunk ^ (row & 7);
    return *(const bf16x8*)(lds + row * BK + cp * 8);
}

// OUTMODE: 2 = f16 out, scaled by alpha (scores)
//          3 = f32 out, no bias (final O -> d_out)
//          4 = fused QKV: col3>>10 selects {Q, K, Vt}; Q/K bf16 row-major,
//              V transposed per batch; bias0/1/2 = bq/bk/bv. C = Q base;
//              K at +8M elems, Vt at +16M elems.
template <int OUTMODE>
__global__ __launch_bounds__(256)
void gemm_bt(const bf16* __restrict__ A, const bf16* __restrict__ Bm,
             const float* __restrict__ bias0, const float* __restrict__ bias1,
             const float* __restrict__ bias2, void* __restrict__ C,
             int K, int N, float alpha, long zA, long zB, long zC)
{
    __shared__ alignas(16) bf16 As[2][BM * BK];
    __shared__ alignas(16) bf16 Bs[2][BN * BK];

    const int tid  = threadIdx.x;
    const int lane = tid & 63;
    const int wid  = tid >> 6;
    const int wr   = (wid >> 1) * 64;   // wave row offset in tile
    const int wc   = (wid & 1) * 64;    // wave col offset in tile
    const int quad = lane >> 4;
    const int l16  = lane & 15;

    const int m0 = blockIdx.y * BM;
    const int n0 = blockIdx.x * BN;
    const int z  = blockIdx.z;

    const bf16* Ab = A + (size_t)z * zA + (size_t)m0 * K;
    const bf16* Bb = Bm + (size_t)z * zB + (size_t)n0 * K;

    f32x4 acc[4][4] = {};

    // Prologue: stage tile 0 into buffer 0.
    stage_tile(Ab, K, As[0], tid);
    stage_tile(Bb, K, Bs[0], tid);

    const int niter = K / BK;
    for (int it = 0; it < niter; ++it) {
        const int cur = it & 1;
        __syncthreads();   // drains vmcnt: buf[cur] staged; prior compute done
        if (it + 1 < niter) {
            stage_tile(Ab + (it + 1) * BK, K, As[cur ^ 1], tid);
            stage_tile(Bb + (it + 1) * BK, K, Bs[cur ^ 1], tid);
        }
#pragma unroll
        for (int h = 0; h < 2; ++h) {
            bf16x8 af[4], bfr[4];
#pragma unroll
            for (int i = 0; i < 4; ++i)
                af[i]  = read_frag(As[cur], wr + i * 16 + l16, h * 4 + quad);
#pragma unroll
            for (int j = 0; j < 4; ++j)
                bfr[j] = read_frag(Bs[cur], wc + j * 16 + l16, h * 4 + quad);

#pragma unroll
            for (int i = 0; i < 4; ++i)
#pragma unroll
                for (int j = 0; j < 4; ++j)
                    acc[i][j] = __builtin_amdgcn_mfma_f32_16x16x32_bf16(
                        af[i], bfr[j], acc[i][j], 0, 0, 0);
        }
    }

    // Epilogue. C/D layout (verified m89): col = lane&15, row = quad*4 + reg.
#pragma unroll
    for (int j = 0; j < 4; ++j) {
        const int col3 = n0 + wc + j * 16 + l16;
#pragma unroll
        for (int i = 0; i < 4; ++i) {
            const int rbase = m0 + wr + i * 16 + quad * 4;
            if (OUTMODE == 2) {
                f16* Cf = (f16*)C + (size_t)z * zC;
#pragma unroll
                for (int r = 0; r < 4; ++r)
                    Cf[(size_t)(rbase + r) * N + col3] = (f16)(acc[i][j][r] * alpha);
            } else if (OUTMODE == 3) {
                float* Cf = (float*)C + (size_t)z * zC;
#pragma unroll
                for (int r = 0; r < 4; ++r)
                    Cf[(size_t)(rbase + r) * N + col3] = acc[i][j][r];
            } else { // OUTMODE == 4
                const int mat = col3 >> 10;           // 0=Q 1=K 2=V (uniform per j)
                const int col = col3 & 1023;
                const float* bp = (mat == 0) ? bias0 : (mat == 1) ? bias1 : bias2;
                const float bj = bp[col];
                if (mat < 2) {
                    bf16* Cb = (bf16*)C + (size_t)mat * (8u << 20);
#pragma unroll
                    for (int r = 0; r < 4; ++r)
                        Cb[(size_t)(rbase + r) * 1024 + col] =
                            (bf16)(acc[i][j][r] + bj);
                } else {
                    // Vt[b][col][s] = V[b*2048+s][col]; quad rows are 4
                    // consecutive s -> one 8B same-type vector store.
                    bf16* Cb = (bf16*)C + (size_t)(16u << 20);
                    const int b = rbase >> 11;
                    const int s = rbase & 2047;
                    bf16x4 tmp;
#pragma unroll
                    for (int r = 0; r < 4; ++r) tmp[r] = (bf16)(acc[i][j][r] + bj);
                    *(bf16x4*)(Cb + (((size_t)((b << 10) + col)) << 11) + s) = tmp;
                }
            }
        }
    }
}

__device__ __forceinline__ float wred_max(float v)
{
#pragma unroll
    for (int o = 32; o > 0; o >>= 1) v = fmaxf(v, __shfl_xor(v, o, 64));
    return v;
}
__device__ __forceinline__ float wred_sum(float v)
{
#pragma unroll
    for (int o = 32; o > 0; o >>= 1) v += __shfl_xor(v, o, 64);
    return v;
}

__global__ __launch_bounds__(256)
void softmax_rows(const f16* __restrict__ Sc, bf16* __restrict__ P)
{
    constexpr int NC = 2048;
    const size_t row = blockIdx.x;
    const f16* src = Sc + row * NC;
    bf16* dst = P + row * NC;
    const int tid = threadIdx.x;

    float v[8];
    float m = -3.4e38f;
#pragma unroll
    for (int i = 0; i < 8; ++i) {
        v[i] = (float)src[tid + 256 * i];
        m = fmaxf(m, v[i]);
    }
    m = wred_max(m);

    __shared__ float redm[4], reds[4];
    if ((tid & 63) == 0) redm[tid >> 6] = m;
    __syncthreads();
    m = fmaxf(fmaxf(redm[0], redm[1]), fmaxf(redm[2], redm[3]));

    float s = 0.f;
#pragma unroll
    for (int i = 0; i < 8; ++i) { v[i] = __expf(v[i] - m); s += v[i]; }
    s = wred_sum(s);
    if ((tid & 63) == 0) reds[tid >> 6] = s;
    __syncthreads();
    s = reds[0] + reds[1] + reds[2] + reds[3];

    const float inv = 1.f / s;
#pragma unroll
    for (int i = 0; i < 8; ++i) dst[tid + 256 * i] = (bf16)(v[i] * inv);
}

extern "C" void kernel_launch(void* const* d_in, const int* in_sizes, int n_in,
                              void* d_out, int out_size, void* d_ws, size_t ws_size,
                              hipStream_t stream)
{
    constexpr int B = 4, S = 2048, H = 1024;
    const float* x  = (const float*)d_in[0];
    const float* Wq = (const float*)d_in[1];
    const float* bq = (const float*)d_in[2];
    const float* Wk = (const float*)d_in[3];
    const float* bk = (const float*)d_in[4];
    const float* Wv = (const float*)d_in[5];
    const float* bv = (const float*)d_in[6];
    float* out = (float*)d_out;

    char* ws = (char*)d_ws;
    bf16* xb   = (bf16*)ws;                         // 16 MB
    bf16* Wqkv = (bf16*)(ws + (size_t)(16 << 20));  //  6 MB (Wq|Wk|Wv bf16)
    bf16* Q    = (bf16*)(ws + (size_t)(22 << 20));  // 16 MB
    bf16* Kp   = (bf16*)(ws + (size_t)(38 << 20));  // 16 MB (Q + 8M elems)
    bf16* Vt   = (bf16*)(ws + (size_t)(54 << 20));  // 16 MB (Q + 16M elems)
    f16*  Sc   = (f16*) (ws + (size_t)(70 << 20));  // 32 MB (fp16 scores)
    bf16* P    = (bf16*)(ws + (size_t)(22 << 20));  // 32 MB, overlays Q|Kp

    dim3 blk(256, 1, 1);

    // fp32 -> bf16 conversions (Wq/Wk/Wv land contiguously in Wqkv)
    cvt_f32_bf16<<<dim3((B * S * H) / 1024), blk, 0, stream>>>(x, xb, (B * S * H) / 4);
    cvt_f32_bf16<<<dim3((H * H) / 1024), blk, 0, stream>>>(Wq, Wqkv, (H * H) / 4);
    cvt_f32_bf16<<<dim3((H * H) / 1024), blk, 0, stream>>>(Wk, Wqkv + (size_t)H * H, (H * H) / 4);
    cvt_f32_bf16<<<dim3((H * H) / 1024), blk, 0, stream>>>(Wv, Wqkv + 2 * (size_t)H * H, (H * H) / 4);

    // Fused QKV projection: M = 8192, N = 3072, K = 1024 -> Q, Kp, Vt
    gemm_bt<4><<<dim3(3 * H / BN, (B * S) / BM, 1), blk, 0, stream>>>(
        xb, Wqkv, bq, bk, bv, Q, H, 3 * H, 1.0f, 0, 0, 0);

    // Scores: per batch (grid.z), Sc = Q·Kᵀ / 32, fp16
    gemm_bt<2><<<dim3(S / BN, S / BM, B), blk, 0, stream>>>(
        Q, Kp, nullptr, nullptr, nullptr, Sc, H, S, 0.03125f,
        (long)S * H, (long)S * H, (long)S * S);

    // Row softmax: 8192 rows of 2048
    softmax_rows<<<dim3(B * S), blk, 0, stream>>>(Sc, P);

    // O = P·Vtᵀ -> out (fp32)
    gemm_bt<3><<<dim3(H / BN, S / BM, B), blk, 0, stream>>>(
        P, Vt, nullptr, nullptr, nullptr, out, S, H, 1.0f,
        (long)S * S, (long)H * S, (long)S * H);
}